// Round 1
// baseline (318.851 us; speedup 1.0000x reference)
//
#include <hip/hip_runtime.h>

#define H 32
#define Q 64
#define S 8192
#define D 128
#define OBS 16
#define L 2048

// Single fused kernel: 256 blocks x 1024 threads, all co-resident (1 block/CU,
// LDS 48.5 KB, VGPR capped by __launch_bounds__(1024) => <=128).
// Phase 1 (all blocks): priority chunk, then atomicAdd(pdone[head]).
// Phase 2 (blocks 0..31): wait pdone==8, exact top-L select, set sflag[head].
// Phase 3 (all blocks): wait sflag[bid>>3], gather 256 K/V rows per block.
// Flag sync: release = syncthreads + threadfence + atomic; acquire = atomic
// poll + threadfence (device-scope, valid across non-coherent XCD L2s).
__global__ __launch_bounds__(1024) void k_fused(
    const float* __restrict__ attn,
    const float* __restrict__ kv_k,
    const float* __restrict__ kv_v,
    float* __restrict__ prio,
    int* __restrict__ keep,
    int* __restrict__ pdone,
    int* __restrict__ sflag,
    float* __restrict__ out,
    float* __restrict__ hist_out,
    float* __restrict__ pos_out)
{
    __shared__ float pr[S];            // 32 KB priority row (select phase)
    __shared__ int whist[16][257];     // per-wave histograms, bank-decorrelated
    __shared__ int wtot[16];
    __shared__ int res_byte, res_k;

    const int bid = blockIdx.x;
    const int tid = threadIdx.x;
    const int lane = tid & 63, wid = tid >> 6;

    // ---------------- Phase 1: priority (threads 0..255 of every block) ----
    if (tid < 256) {
        const int h = bid >> 3;            // 32 heads x 8 chunks
        const int chunk = bid & 7;
        const int s4 = chunk * 1024 + tid * 4;
        const float4* base = (const float4*)(attn + ((size_t)(h * Q + (Q - OBS)) * S + s4));
        float4 acc = make_float4(0.f, 0.f, 0.f, 0.f);
#pragma unroll
        for (int qq = 0; qq < OBS; ++qq) {
            float4 v = base[qq * (S / 4)];
            acc.x += v.x; acc.y += v.y; acc.z += v.z; acc.w += v.w;
        }
        const float inv = 1.0f / (float)OBS;
        acc.x *= inv; acc.y *= inv; acc.z *= inv; acc.w *= inv;
        *((float4*)(prio + (size_t)(bid >> 3) * S + s4)) = acc;
    }
    __syncthreads();                       // all chunk stores retired (vmcnt drain)
    if (tid == 0) {
        __threadfence();                   // release to device scope
        atomicAdd(&pdone[bid >> 3], 1);
    }

    // ---------------- Phase 2: select (blocks 0..31, one head each) --------
    if (bid < H) {
        const int h = bid;
        if (tid == 0) {
            while (atomicAdd(&pdone[h], 0) < 8) __builtin_amdgcn_s_sleep(2);
            __threadfence();               // acquire: invalidate stale cache
        }
        __syncthreads();

        // ---- load priority row (float4) ----
        {
            const float4* src = (const float4*)(prio + (size_t)h * S);
            ((float4*)pr)[tid] = src[tid];
            ((float4*)pr)[tid + 1024] = src[tid + 1024];
        }
        __syncthreads();

        // ---- pooled keys (positive floats -> monotone uint bits) ----
        unsigned key[8];
        const int s0 = tid * 8;
        {
            float w[12];
#pragma unroll
            for (int i = 0; i < 12; ++i) {
                int idx = s0 - 2 + i;
                w[i] = (idx >= 0 && idx < S) ? pr[idx] : 0.f;
            }
#pragma unroll
            for (int j = 0; j < 8; ++j) {
                int s = s0 + j;
                float pooled;
                if (s >= S - OBS) {
                    pooled = 1.0f;
                } else {
                    int lo = s - 2; if (lo < 0) lo = 0;
                    int hi = s + 3;
                    float sum = 0.f;
                    for (int i = lo; i < hi; ++i) sum += w[i - s0 + 2];
                    pooled = sum / (float)(hi - lo);
                }
                key[j] = __float_as_uint(pooled);
            }
        }

        // ---- 4-pass byte-histogram top-L select ----
        unsigned prefix = 0;
        int k = L;
        for (int pass = 3; pass >= 0; --pass) {
            for (int i = tid; i < 16 * 257; i += 1024) ((int*)whist)[i] = 0;
            __syncthreads();
            const int shift = pass * 8;
            {
                int cur = -1, run = 0;
#pragma unroll
                for (int j = 0; j < 8; ++j) {
                    unsigned kk = key[j];
                    bool match = (pass == 3) || ((kk >> (shift + 8)) == prefix);
                    int b = match ? (int)((kk >> shift) & 255u) : -1;
                    if (b != cur) {
                        if (cur >= 0) atomicAdd(&whist[wid][cur], run);
                        cur = b; run = 1;
                    } else {
                        run++;
                    }
                }
                if (cur >= 0) atomicAdd(&whist[wid][cur], run);
            }
            __syncthreads();
            if (wid == 0) {
                int b0 = 0, b1 = 0, b2 = 0, b3 = 0;
                const int bb0 = 4 * lane;
#pragma unroll
                for (int w = 0; w < 16; ++w) {
                    b0 += whist[w][bb0 + 0];
                    b1 += whist[w][bb0 + 1];
                    b2 += whist[w][bb0 + 2];
                    b3 += whist[w][bb0 + 3];
                }
                int lane_sum = b0 + b1 + b2 + b3;
                int suffix = lane_sum;
#pragma unroll
                for (int off = 1; off < 64; off <<= 1) {
                    int u = __shfl_down(suffix, off);
                    if (lane + off < 64) suffix += u;
                }
                int suffix_next = suffix - lane_sum;
                if (suffix >= k && suffix_next < k) {
                    int bins[4] = {b0, b1, b2, b3};
                    int cum = suffix_next;
                    for (int bb = 3; bb >= 0; --bb) {
                        int nc = cum + bins[bb];
                        if (nc >= k) { res_byte = bb0 + bb; res_k = k - cum; break; }
                        cum = nc;
                    }
                }
            }
            __syncthreads();
            prefix = (prefix << 8) | (unsigned)res_byte;
            k = res_k;
        }
        const unsigned T = prefix;
        const int needed_eq = k;

        // ---- single packed (gt,eq) scan -> output ranks ----
        int gt = 0, eq = 0;
#pragma unroll
        for (int j = 0; j < 8; ++j) {
            gt += (key[j] > T) ? 1 : 0;
            eq += (key[j] == T) ? 1 : 0;
        }
        int packed = (gt << 16) | eq;
        int v = packed;
#pragma unroll
        for (int off = 1; off < 64; off <<= 1) {
            int u = __shfl_up(v, off);
            if (lane >= off) v += u;
        }
        if (lane == 63) wtot[wid] = v;
        __syncthreads();
        int base = 0;
        for (int w = 0; w < wid; ++w) base += wtot[w];
        int excl = base + v - packed;
        int gt_before = excl >> 16;
        int eq_before = excl & 0xffff;

        // ---- epilogue: scattered writes in index order ----
        {
            int g = gt_before, e = eq_before;
#pragma unroll
            for (int j = 0; j < 8; ++j) {
                bool isgt = key[j] > T;
                bool iseq = key[j] == T;
                bool sel = isgt || (iseq && (e < needed_eq));
                if (sel) {
                    int s = s0 + j;
                    int rank = g + (e < needed_eq ? e : needed_eq);
                    size_t o = (size_t)h * L + rank;
                    keep[o] = s;
                    pos_out[o] = (float)s;
                    hist_out[o] = pr[s];
                }
                g += isgt ? 1 : 0;
                e += iseq ? 1 : 0;
            }
        }
        __syncthreads();                   // all keep/hist/pos stores retired
        if (tid == 0) {
            __threadfence();               // release
            atomicExch(&sflag[h], 1);
        }
    }

    // ---------------- Phase 3: gather (all blocks; 256 rows per block) -----
    {
        const int h = bid >> 3;            // all 32 groups of this block share one head
        if (tid == 0) {
            while (atomicAdd(&sflag[h], 0) == 0) __builtin_amdgcn_s_sleep(2);
            __threadfence();               // acquire
        }
        __syncthreads();
        const int g = (bid << 5) | (tid >> 5);   // 8192 groups of 32 lanes
        const int l32 = tid & 31;
        const int r0 = g << 3;                   // 8 consecutive row-pairs per group
#pragma unroll 2
        for (int j = 0; j < 8; ++j) {
            const int idx = r0 + j;              // h*L + r, sorted ascending
            const int s = keep[idx];
            const float4* srcK = (const float4*)(kv_k + (size_t)(h * S + s) * D);
            const float4* srcV = (const float4*)(kv_v + (size_t)(h * S + s) * D);
            float4* dstK = (float4*)(out + (size_t)idx * D);
            float4* dstV = (float4*)(out + ((size_t)H * L + idx) * D);
            dstK[l32] = srcK[l32];
            dstV[l32] = srcV[l32];
        }
    }
}

extern "C" void kernel_launch(void* const* d_in, const int* in_sizes, int n_in,
                              void* d_out, int out_size, void* d_ws, size_t ws_size,
                              hipStream_t stream) {
    const float* attn = (const float*)d_in[0];
    const float* k_val = (const float*)d_in[1];
    const float* v_val = (const float*)d_in[2];

    float* out = (float*)d_out;
    float* hist = out + (size_t)2 * H * L * D;
    float* pos = hist + (size_t)H * L;

    // ws layout: [0,256) flags (pdone[32], sflag[32], padding) | prio H*S | keep H*L
    int* pdone = (int*)d_ws;
    int* sflag = pdone + 32;
    float* prio = (float*)((char*)d_ws + 256);
    int* keep = (int*)((char*)d_ws + 256 + (size_t)H * S * sizeof(float));

    hipMemsetAsync(d_ws, 0, 256, stream);   // zero flags (ws is poisoned each iter)
    k_fused<<<256, 1024, 0, stream>>>(attn, k_val, v_val, prio, keep, pdone, sflag,
                                      out, hist, pos);
}

// Round 2
// 318.434 us; speedup vs baseline: 1.0013x; 1.0013x over previous
//
#include <hip/hip_runtime.h>

#define H 32
#define Q 64
#define S 8192
#define D 128
#define OBS 16
#define L 2048

// Kernel 1: priority[h][s] = mean over last OBS queries of attn[0,h,q,s].
// Wide: 256 blocks so the 16 MiB attn read uses all CUs.
// Block 0 additionally zeroes the select-done flags (ws is poisoned each iter);
// the kernel boundary orders this before k2's polls.
__global__ void k_priority(const float* __restrict__ attn, float* __restrict__ prio,
                           int* __restrict__ sflag) {
    if (blockIdx.x == 0 && threadIdx.x < H) sflag[threadIdx.x * 32] = 0;
    int gid = blockIdx.x;              // 0..255
    int h = gid >> 3;                  // 32 heads
    int chunk = gid & 7;               // 8 chunks of 1024 floats
    int s4 = chunk * 1024 + threadIdx.x * 4;
    const float4* base = (const float4*)(attn + ((size_t)(h * Q + (Q - OBS)) * S + s4));
    float4 acc = make_float4(0.f, 0.f, 0.f, 0.f);
#pragma unroll
    for (int qq = 0; qq < OBS; ++qq) {
        float4 v = base[qq * (S / 4)];
        acc.x += v.x; acc.y += v.y; acc.z += v.z; acc.w += v.w;
    }
    const float inv = 1.0f / (float)OBS;
    acc.x *= inv; acc.y *= inv; acc.z *= inv; acc.w *= inv;
    *((float4*)(prio + (size_t)h * S + s4)) = acc;
}

// Kernel 2: fused select + gather. 256 blocks x 1024 threads, all co-resident
// (LDS 98.6 KB -> 1 block/CU, grid == CU count).
//   blocks 0..31 : exact top-L select for head h=bid (prio valid via kernel
//                  boundary, no entry wait), then release sflag[h].
//   all blocks   : gather 256 K/V row-pairs for head bid>>3 after acquiring
//                  that head's flag (agent-scope atomic load, padded flags).
__global__ __launch_bounds__(1024) void k_selgather(
    const float* __restrict__ prio,
    const float* __restrict__ kv_k,
    const float* __restrict__ kv_v,
    int* __restrict__ keep,
    int* __restrict__ sflag,
    float* __restrict__ out,
    float* __restrict__ hist_out,
    float* __restrict__ pos_out)
{
    __shared__ float pr[S];            // 32 KB priority row
    __shared__ int whist[4][16][257];  // per-pass, per-wave histograms (zeroed once)
    __shared__ int wtot[16];
    __shared__ int res_byte, res_k;

    const int bid = blockIdx.x;
    const int tid = threadIdx.x;
    const int lane = tid & 63, wid = tid >> 6;

    // ---------------- select (blocks 0..31) ----------------
    if (bid < H) {
        const int h = bid;

        // load priority row (float4) + zero ALL four pass-histograms once
        {
            const float4* src = (const float4*)(prio + (size_t)h * S);
            ((float4*)pr)[tid] = src[tid];
            ((float4*)pr)[tid + 1024] = src[tid + 1024];
            for (int i = tid; i < 4 * 16 * 257; i += 1024) ((int*)whist)[i] = 0;
        }
        __syncthreads();

        // pooled keys (positive floats -> monotone uint bits)
        unsigned key[8];
        const int s0 = tid * 8;
        {
            float w[12];
#pragma unroll
            for (int i = 0; i < 12; ++i) {
                int idx = s0 - 2 + i;
                w[i] = (idx >= 0 && idx < S) ? pr[idx] : 0.f;
            }
#pragma unroll
            for (int j = 0; j < 8; ++j) {
                int s = s0 + j;
                float pooled;
                if (s >= S - OBS) {
                    pooled = 1.0f;
                } else {
                    int lo = s - 2; if (lo < 0) lo = 0;
                    int hi = s + 3;
                    float sum = 0.f;
                    for (int i = lo; i < hi; ++i) sum += w[i - s0 + 2];
                    pooled = sum / (float)(hi - lo);
                }
                key[j] = __float_as_uint(pooled);
            }
        }

        // 4-pass byte-histogram top-L select (2 barriers/pass)
        unsigned prefix = 0;
        int k = L;
        for (int pass = 3; pass >= 0; --pass) {
            const int shift = pass * 8;
            {
                int cur = -1, run = 0;
#pragma unroll
                for (int j = 0; j < 8; ++j) {
                    unsigned kk = key[j];
                    bool match = (pass == 3) || ((kk >> (shift + 8)) == prefix);
                    int b = match ? (int)((kk >> shift) & 255u) : -1;
                    if (b != cur) {
                        if (cur >= 0) atomicAdd(&whist[pass][wid][cur], run);
                        cur = b; run = 1;
                    } else {
                        run++;
                    }
                }
                if (cur >= 0) atomicAdd(&whist[pass][wid][cur], run);
            }
            __syncthreads();
            if (wid == 0) {
                int b0 = 0, b1 = 0, b2 = 0, b3 = 0;
                const int bb0 = 4 * lane;
#pragma unroll
                for (int w = 0; w < 16; ++w) {
                    b0 += whist[pass][w][bb0 + 0];
                    b1 += whist[pass][w][bb0 + 1];
                    b2 += whist[pass][w][bb0 + 2];
                    b3 += whist[pass][w][bb0 + 3];
                }
                int lane_sum = b0 + b1 + b2 + b3;
                int suffix = lane_sum;
#pragma unroll
                for (int off = 1; off < 64; off <<= 1) {
                    int u = __shfl_down(suffix, off);
                    if (lane + off < 64) suffix += u;
                }
                int suffix_next = suffix - lane_sum;
                if (suffix >= k && suffix_next < k) {
                    int bins[4] = {b0, b1, b2, b3};
                    int cum = suffix_next;
                    for (int bb = 3; bb >= 0; --bb) {
                        int nc = cum + bins[bb];
                        if (nc >= k) { res_byte = bb0 + bb; res_k = k - cum; break; }
                        cum = nc;
                    }
                }
            }
            __syncthreads();
            prefix = (prefix << 8) | (unsigned)res_byte;
            k = res_k;
        }
        const unsigned T = prefix;
        const int needed_eq = k;

        // single packed (gt,eq) scan -> output ranks
        int gt = 0, eq = 0;
#pragma unroll
        for (int j = 0; j < 8; ++j) {
            gt += (key[j] > T) ? 1 : 0;
            eq += (key[j] == T) ? 1 : 0;
        }
        int packed = (gt << 16) | eq;
        int v = packed;
#pragma unroll
        for (int off = 1; off < 64; off <<= 1) {
            int u = __shfl_up(v, off);
            if (lane >= off) v += u;
        }
        if (lane == 63) wtot[wid] = v;
        __syncthreads();
        int base = 0;
        for (int w = 0; w < wid; ++w) base += wtot[w];
        int excl = base + v - packed;
        int gt_before = excl >> 16;
        int eq_before = excl & 0xffff;

        // epilogue: scattered writes in index order
        {
            int g = gt_before, e = eq_before;
#pragma unroll
            for (int j = 0; j < 8; ++j) {
                bool isgt = key[j] > T;
                bool iseq = key[j] == T;
                bool sel = isgt || (iseq && (e < needed_eq));
                if (sel) {
                    int s = s0 + j;
                    int rank = g + (e < needed_eq ? e : needed_eq);
                    size_t o = (size_t)h * L + rank;
                    keep[o] = s;
                    pos_out[o] = (float)s;
                    hist_out[o] = pr[s];
                }
                g += isgt ? 1 : 0;
                e += iseq ? 1 : 0;
            }
        }
        __syncthreads();                   // all keep stores retired (vmcnt drain)
        if (tid == 0) {
            __threadfence();               // writeback this XCD's L2 (release)
            __hip_atomic_store(&sflag[h * 32], 1, __ATOMIC_RELEASE,
                               __HIP_MEMORY_SCOPE_AGENT);
        }
    }

    // ---------------- gather (all blocks; 256 row-pairs each) ----------------
    {
        const int gh = bid >> 3;
        if (tid == 0) {
            // agent-scope load polls Infinity Cache; no atomic-unit traffic
            while (__hip_atomic_load(&sflag[gh * 32], __ATOMIC_ACQUIRE,
                                     __HIP_MEMORY_SCOPE_AGENT) == 0)
                __builtin_amdgcn_s_sleep(8);
            __threadfence();               // invalidate caches (acquire)
        }
        __syncthreads();

        const int r0 = ((bid << 5) | (tid >> 5)) << 3;  // 8 pairs per 32-lane group
        const int l32 = tid & 31;
#pragma unroll
        for (int jj = 0; jj < 8; jj += 4) {
            int sI[4];
#pragma unroll
            for (int t = 0; t < 4; ++t) sI[t] = keep[r0 + jj + t];   // 4 independent
#pragma unroll
            for (int t = 0; t < 4; ++t) {
                const int idx = r0 + jj + t;
                const float4* srcK = (const float4*)(kv_k + (size_t)(gh * S + sI[t]) * D);
                const float4* srcV = (const float4*)(kv_v + (size_t)(gh * S + sI[t]) * D);
                ((float4*)(out + (size_t)idx * D))[l32] = srcK[l32];
                ((float4*)(out + ((size_t)H * L + idx) * D))[l32] = srcV[l32];
            }
        }
    }
}

extern "C" void kernel_launch(void* const* d_in, const int* in_sizes, int n_in,
                              void* d_out, int out_size, void* d_ws, size_t ws_size,
                              hipStream_t stream) {
    const float* attn = (const float*)d_in[0];
    const float* k_val = (const float*)d_in[1];
    const float* v_val = (const float*)d_in[2];

    float* out = (float*)d_out;
    float* hist = out + (size_t)2 * H * L * D;
    float* pos = hist + (size_t)H * L;

    // ws layout: sflag[32*32] ints (padded, 4 KB) | prio H*S floats | keep H*L ints
    int* sflag = (int*)d_ws;
    float* prio = (float*)((char*)d_ws + 4096);
    int* keep = (int*)((char*)d_ws + 4096 + (size_t)H * S * sizeof(float));

    k_priority<<<256, 256, 0, stream>>>(attn, prio, sflag);
    k_selgather<<<256, 1024, 0, stream>>>(prio, k_val, v_val, keep, sflag,
                                          out, hist, pos);
}

// Round 3
// 288.393 us; speedup vs baseline: 1.1056x; 1.1042x over previous
//
#include <hip/hip_runtime.h>

#define H 32
#define Q 64
#define S 8192
#define D 128
#define OBS 16
#define L 2048

typedef float f32x4 __attribute__((ext_vector_type(4)));

// Kernel 1: fused priority + exact top-L select. One 1024-thread block per head.
// Reads this head's last-OBS attn rows directly (512 KB, 32 indep streams/thread),
// computes priority into LDS (no global prio round-trip), then the verified
// 4-pass byte-histogram select with all pass-histograms pre-zeroed once.
__global__ __launch_bounds__(1024) void k_priosel(
    const float* __restrict__ attn,
    int* __restrict__ keep,
    float* __restrict__ hist_out,
    float* __restrict__ pos_out)
{
    __shared__ float pr[S];            // 32 KB priority row
    __shared__ int whist[4][16][257];  // per-pass per-wave histograms
    __shared__ int wtot[16];
    __shared__ int res_byte, res_k;

    const int h = blockIdx.x;
    const int tid = threadIdx.x;
    const int lane = tid & 63, wid = tid >> 6;

    // ---- zero all 4 pass-histograms (overlaps with attn loads below) ----
    for (int i = tid; i < 4 * 16 * 257; i += 1024) ((int*)whist)[i] = 0;

    // ---- priority: mean of last OBS attn rows, directly from global ----
    {
        const float* abase = attn + (size_t)(h * Q + (Q - OBS)) * S;
        f32x4 a0 = {0.f, 0.f, 0.f, 0.f}, a1 = a0;
#pragma unroll
        for (int q = 0; q < OBS; ++q) {
            const f32x4* row = (const f32x4*)(abase + (size_t)q * S);
            a0 += __builtin_nontemporal_load(row + tid);
            a1 += __builtin_nontemporal_load(row + tid + 1024);
        }
        const float inv = 1.0f / (float)OBS;
        ((f32x4*)pr)[tid] = a0 * inv;
        ((f32x4*)pr)[tid + 1024] = a1 * inv;
    }
    __syncthreads();

    // ---- pooled keys (positive floats -> monotone uint bits) ----
    unsigned key[8];
    const int s0 = tid * 8;
    {
        float w[12];
#pragma unroll
        for (int i = 0; i < 12; ++i) {
            int idx = s0 - 2 + i;
            w[i] = (idx >= 0 && idx < S) ? pr[idx] : 0.f;
        }
#pragma unroll
        for (int j = 0; j < 8; ++j) {
            int s = s0 + j;
            float pooled;
            if (s >= S - OBS) {
                pooled = 1.0f;
            } else {
                int lo = s - 2; if (lo < 0) lo = 0;
                int hi = s + 3;
                float sum = 0.f;
                for (int i = lo; i < hi; ++i) sum += w[i - s0 + 2];
                pooled = sum / (float)(hi - lo);
            }
            key[j] = __float_as_uint(pooled);
        }
    }

    // ---- 4-pass byte-histogram top-L select (2 barriers/pass) ----
    unsigned prefix = 0;
    int k = L;
    for (int pass = 3; pass >= 0; --pass) {
        const int shift = pass * 8;
        {
            int cur = -1, run = 0;
#pragma unroll
            for (int j = 0; j < 8; ++j) {
                unsigned kk = key[j];
                bool match = (pass == 3) || ((kk >> (shift + 8)) == prefix);
                int b = match ? (int)((kk >> shift) & 255u) : -1;
                if (b != cur) {
                    if (cur >= 0) atomicAdd(&whist[pass][wid][cur], run);
                    cur = b; run = 1;
                } else {
                    run++;
                }
            }
            if (cur >= 0) atomicAdd(&whist[pass][wid][cur], run);
        }
        __syncthreads();
        if (wid == 0) {
            int b0 = 0, b1 = 0, b2 = 0, b3 = 0;
            const int bb0 = 4 * lane;
#pragma unroll
            for (int w = 0; w < 16; ++w) {
                b0 += whist[pass][w][bb0 + 0];
                b1 += whist[pass][w][bb0 + 1];
                b2 += whist[pass][w][bb0 + 2];
                b3 += whist[pass][w][bb0 + 3];
            }
            int lane_sum = b0 + b1 + b2 + b3;
            int suffix = lane_sum;   // inclusive suffix over lanes
#pragma unroll
            for (int off = 1; off < 64; off <<= 1) {
                int u = __shfl_down(suffix, off);
                if (lane + off < 64) suffix += u;
            }
            int suffix_next = suffix - lane_sum;
            if (suffix >= k && suffix_next < k) {
                int bins[4] = {b0, b1, b2, b3};
                int cum = suffix_next;
                for (int bb = 3; bb >= 0; --bb) {
                    int nc = cum + bins[bb];
                    if (nc >= k) { res_byte = bb0 + bb; res_k = k - cum; break; }
                    cum = nc;
                }
            }
        }
        __syncthreads();
        prefix = (prefix << 8) | (unsigned)res_byte;
        k = res_k;
    }
    const unsigned T = prefix;
    const int needed_eq = k;

    // ---- single packed (gt,eq) scan -> output ranks ----
    int gt = 0, eq = 0;
#pragma unroll
    for (int j = 0; j < 8; ++j) {
        gt += (key[j] > T) ? 1 : 0;
        eq += (key[j] == T) ? 1 : 0;
    }
    int packed = (gt << 16) | eq;
    int v = packed;
#pragma unroll
    for (int off = 1; off < 64; off <<= 1) {
        int u = __shfl_up(v, off);
        if (lane >= off) v += u;
    }
    if (lane == 63) wtot[wid] = v;
    __syncthreads();
    int base = 0;
    for (int w = 0; w < wid; ++w) base += wtot[w];
    int excl = base + v - packed;
    int gt_before = excl >> 16;
    int eq_before = excl & 0xffff;

    // ---- epilogue: scattered writes in index order (already sorted) ----
    {
        int g = gt_before, e = eq_before;
#pragma unroll
        for (int j = 0; j < 8; ++j) {
            bool isgt = key[j] > T;
            bool iseq = key[j] == T;
            bool sel = isgt || (iseq && (e < needed_eq));
            if (sel) {
                int s = s0 + j;
                int rank = g + (e < needed_eq ? e : needed_eq);
                size_t o = (size_t)h * L + rank;
                keep[o] = s;
                pos_out[o] = (float)s;
                hist_out[o] = pr[s];
            }
            g += isgt ? 1 : 0;
            e += iseq ? 1 : 0;
        }
    }
}

// Kernel 2: gather selected K/V rows. 2048 blocks x 256 threads; each 32-lane
// group handles 4 consecutive ranks: one broadcast int4 keep-load, then 8
// independent 512B row copies in flight (nontemporal: streamed, no reuse).
__global__ void k_gather(const float* __restrict__ kv_k, const float* __restrict__ kv_v,
                         const int* __restrict__ keep, float* __restrict__ out) {
    const int tid = threadIdx.x;
    const int l32 = tid & 31;
    const int i0 = (blockIdx.x * 8 + (tid >> 5)) * 4;   // h*L + rank, 4-aligned
    const int h = i0 >> 11;                             // same head for all 4
    const int4 kk = *(const int4*)(keep + i0);          // broadcast 16B load
    const int sI[4] = {kk.x, kk.y, kk.z, kk.w};
#pragma unroll
    for (int t = 0; t < 4; ++t) {
        const int idx = i0 + t;
        const f32x4* srcK = (const f32x4*)(kv_k + (size_t)(h * S + sI[t]) * D);
        const f32x4* srcV = (const f32x4*)(kv_v + (size_t)(h * S + sI[t]) * D);
        f32x4* dstK = (f32x4*)(out + (size_t)idx * D);
        f32x4* dstV = (f32x4*)(out + ((size_t)H * L + idx) * D);
        __builtin_nontemporal_store(__builtin_nontemporal_load(srcK + l32), dstK + l32);
        __builtin_nontemporal_store(__builtin_nontemporal_load(srcV + l32), dstV + l32);
    }
}

extern "C" void kernel_launch(void* const* d_in, const int* in_sizes, int n_in,
                              void* d_out, int out_size, void* d_ws, size_t ws_size,
                              hipStream_t stream) {
    const float* attn = (const float*)d_in[0];
    const float* k_val = (const float*)d_in[1];
    const float* v_val = (const float*)d_in[2];

    float* out = (float*)d_out;
    float* hist = out + (size_t)2 * H * L * D;
    float* pos = hist + (size_t)H * L;

    int* keep = (int*)d_ws;   // H*L ints, 16B-aligned

    k_priosel<<<H, 1024, 0, stream>>>(attn, keep, hist, pos);
    k_gather<<<(H * L) / 32, 256, 0, stream>>>(k_val, v_val, keep, out);
}